// Round 2
// baseline (396.948 us; speedup 1.0000x reference)
//
#include <hip/hip_runtime.h>
#include <math.h>

// ARAP projection, 8 Adam steps. N=100000 vertices, K=8 CSR neighbors.
// Per step: kernel A computes per-vertex rotation R_i (polar of S_i^T via
// scaled Newton iteration + det<0 reflection correction matching SVD ref);
// kernel B gathers the ARAP gradient (needs all R) and applies Adam.

#define BLK 256

__device__ __forceinline__ void load3(const float* __restrict__ p, int idx,
                                      float& a, float& b, float& c) {
    a = p[3 * idx + 0];
    b = p[3 * idx + 1];
    c = p[3 * idx + 2];
}

__global__ __launch_bounds__(BLK) void rot_kernel(
    const float* __restrict__ xyz, const float* __restrict__ recon,
    const int* __restrict__ nbr, const int* __restrict__ num,
    const int* __restrict__ acc, const float* __restrict__ wm,
    float* __restrict__ Rout, int n)
{
    int i = blockIdx.x * blockDim.x + threadIdx.x;
    if (i >= n) return;

    float xi0, xi1, xi2, pi0, pi1, pi2;
    load3(xyz, i, xi0, xi1, xi2);
    load3(recon, i, pi0, pi1, pi2);

    int e0 = acc[i];
    int cnt = num[i];

    // S = sum_j w_ij * (x_i - x_j)(p_i - p_j)^T   (S[r][c] = ei[r]*ed[c])
    float S00 = 0.f, S01 = 0.f, S02 = 0.f;
    float S10 = 0.f, S11 = 0.f, S12 = 0.f;
    float S20 = 0.f, S21 = 0.f, S22 = 0.f;

    for (int e = e0; e < e0 + cnt; ++e) {
        int j = nbr[e];
        float w = wm[e];
        float xj0, xj1, xj2, pj0, pj1, pj2;
        load3(xyz, j, xj0, xj1, xj2);
        load3(recon, j, pj0, pj1, pj2);
        float ei0 = xi0 - xj0, ei1 = xi1 - xj1, ei2 = xi2 - xj2;
        float ed0 = pi0 - pj0, ed1 = pi1 - pj1, ed2 = pi2 - pj2;
        float w0 = w * ei0, w1 = w * ei1, w2 = w * ei2;
        S00 += w0 * ed0; S01 += w0 * ed1; S02 += w0 * ed2;
        S10 += w1 * ed0; S11 += w1 * ed1; S12 += w1 * ed2;
        S20 += w2 * ed0; S21 += w2 * ed1; S22 += w2 * ed2;
    }

    float detS = S00*(S11*S22 - S12*S21)
               - S01*(S10*S22 - S12*S20)
               + S02*(S10*S21 - S11*S20);

    // A = M = S^T ; scaled Newton polar iteration -> Q = polar(S^T) = V U^T
    // (for S = U Sigma V^T). det(Q) = sign(det S).
    float A00 = S00, A01 = S10, A02 = S20;
    float A10 = S01, A11 = S11, A12 = S21;
    float A20 = S02, A21 = S12, A22 = S22;

    float fS = A00*A00 + A01*A01 + A02*A02 + A10*A10 + A11*A11 + A12*A12
             + A20*A20 + A21*A21 + A22*A22;
    if (fS < 1e-24f) {
        // degenerate: SVD of ~0 gives identity rotation
        A00 = 1.f; A01 = 0.f; A02 = 0.f;
        A10 = 0.f; A11 = 1.f; A12 = 0.f;
        A20 = 0.f; A21 = 0.f; A22 = 1.f;
    } else {
#pragma unroll
        for (int it = 0; it < 10; ++it) {
            // cofactor matrix C ; A^{-T} = C / det
            float C00 = A11*A22 - A12*A21;
            float C01 = A12*A20 - A10*A22;
            float C02 = A10*A21 - A11*A20;
            float C10 = A02*A21 - A01*A22;
            float C11 = A00*A22 - A02*A20;
            float C12 = A01*A20 - A00*A21;
            float C20 = A01*A12 - A02*A11;
            float C21 = A02*A10 - A00*A12;
            float C22 = A00*A11 - A01*A10;
            float det = A00*C00 + A01*C01 + A02*C02;
            float ad = fmaxf(fabsf(det), 1e-30f);
            det = (det < 0.f) ? -ad : ad;
            float fA = A00*A00 + A01*A01 + A02*A02 + A10*A10 + A11*A11
                     + A12*A12 + A20*A20 + A21*A21 + A22*A22;
            float fC = C00*C00 + C01*C01 + C02*C02 + C10*C10 + C11*C11
                     + C12*C12 + C20*C20 + C21*C21 + C22*C22;
            // Higham Frobenius scaling: g = sqrt(||A^-1||_F / ||A||_F)
            float g = sqrtf(sqrtf(fC / fmaxf(ad * ad * fA, 1e-38f)));
            float s0 = 0.5f * g;
            float s1 = 0.5f / (g * det);
            A00 = s0*A00 + s1*C00; A01 = s0*A01 + s1*C01; A02 = s0*A02 + s1*C02;
            A10 = s0*A10 + s1*C10; A11 = s0*A11 + s1*C11; A12 = s0*A12 + s1*C12;
            A20 = s0*A20 + s1*C20; A21 = s0*A21 + s1*C21; A22 = s0*A22 + s1*C22;
        }

        if (detS < 0.f) {
            // Reference flips last column of V (sigma_3 direction):
            // R = Q (I - 2 u3 u3^T), u3 = smallest-eigenvalue eigenvector of
            // H = Q^T M = U Sigma U^T  (M = S^T, Q[r][c]=A..).
            // H[a][b] = sum_k Q[k][a] * M[k][b],  M[k][b] = S[b][k]
            float H00 = A00*S00 + A10*S01 + A20*S02;
            float H01 = A00*S10 + A10*S11 + A20*S12;
            float H02 = A00*S20 + A10*S21 + A20*S22;
            float H10 = A01*S00 + A11*S01 + A21*S02;
            float H11 = A01*S10 + A11*S11 + A21*S12;
            float H12 = A01*S20 + A11*S21 + A21*S22;
            float H20 = A02*S00 + A12*S01 + A22*S02;
            float H21 = A02*S10 + A12*S11 + A22*S12;
            float H22 = A02*S20 + A12*S21 + A22*S22;
            // symmetrize (H is symmetric PSD up to rounding)
            float h01 = 0.5f*(H01 + H10);
            float h02 = 0.5f*(H02 + H20);
            float h12 = 0.5f*(H12 + H21);

            // eigenvalues of symmetric H (trig closed form), l1>=l2>=l3
            float q = (H00 + H11 + H22) * (1.f/3.f);
            float p1 = h01*h01 + h02*h02 + h12*h12;
            float a00 = H00 - q, a11 = H11 - q, a22 = H22 - q;
            float p2 = a00*a00 + a11*a11 + a22*a22 + 2.f*p1;
            float p  = sqrtf(fmaxf(p2 * (1.f/6.f), 1e-30f));
            float ip = 1.f / p;
            float b00 = a00*ip, b01 = h01*ip, b02 = h02*ip;
            float b11 = a11*ip, b12 = h12*ip, b22 = a22*ip;
            float detB = b00*(b11*b22 - b12*b12)
                       - b01*(b01*b22 - b12*b02)
                       + b02*(b01*b12 - b11*b02);
            float r = fminf(1.f, fmaxf(-1.f, 0.5f*detB));
            float phi = acosf(r) * (1.f/3.f);
            float l1 = q + 2.f*p*cosf(phi);
            float l3 = q + 2.f*p*cosf(phi + 2.0943951023931953f);
            float l2 = 3.f*q - l1 - l3;

            // u3: columns of (H-l1 I)(H-l2 I) are parallel to u3
            float m100 = H00-l1, m111 = H11-l1, m122 = H22-l1;
            float m200 = H00-l2, m211 = H11-l2, m222 = H22-l2;
            // P = M1*M2 (both share off-diagonals h01,h02,h12)
            float P00 = m100*m200 + h01*h01 + h02*h02;
            float P10 = h01*m200 + m111*h01 + h12*h02;
            float P20 = h02*m200 + h12*h01 + m122*h02;
            float P01 = m100*h01 + h01*m211 + h02*h12;
            float P11 = h01*h01 + m111*m211 + h12*h12;
            float P21 = h02*h01 + h12*m211 + m122*h12;
            float P02 = m100*h02 + h01*h12 + h02*m222;
            float P12 = h01*h02 + m111*h12 + h12*m222;
            float P22 = h02*h02 + h12*h12 + m122*m222;

            float n0 = P00*P00 + P10*P10 + P20*P20;
            float n1 = P01*P01 + P11*P11 + P21*P21;
            float n2 = P02*P02 + P12*P12 + P22*P22;
            float u0, u1, u2, nn;
            if (n0 >= n1 && n0 >= n2)      { u0 = P00; u1 = P10; u2 = P20; nn = n0; }
            else if (n1 >= n2)             { u0 = P01; u1 = P11; u2 = P21; nn = n1; }
            else                           { u0 = P02; u1 = P12; u2 = P22; nn = n2; }
            if (nn > 1e-30f) {
                float inv = rsqrtf(nn);
                u0 *= inv; u1 *= inv; u2 *= inv;
                // R = Q - 2 (Q u) u^T
                float Qu0 = A00*u0 + A01*u1 + A02*u2;
                float Qu1 = A10*u0 + A11*u1 + A12*u2;
                float Qu2 = A20*u0 + A21*u1 + A22*u2;
                A00 -= 2.f*Qu0*u0; A01 -= 2.f*Qu0*u1; A02 -= 2.f*Qu0*u2;
                A10 -= 2.f*Qu1*u0; A11 -= 2.f*Qu1*u1; A12 -= 2.f*Qu1*u2;
                A20 -= 2.f*Qu2*u0; A21 -= 2.f*Qu2*u1; A22 -= 2.f*Qu2*u2;
            }
        }
    }

    float* Rp = Rout + (size_t)i * 9;
    Rp[0] = A00; Rp[1] = A01; Rp[2] = A02;
    Rp[3] = A10; Rp[4] = A11; Rp[5] = A12;
    Rp[6] = A20; Rp[7] = A21; Rp[8] = A22;
}

__global__ __launch_bounds__(BLK) void grad_adam_kernel(
    const float* __restrict__ xyz, const float* __restrict__ recon,
    const int* __restrict__ nbr, const int* __restrict__ num,
    const int* __restrict__ acc, const float* __restrict__ wm,
    const float* __restrict__ arapW, const float* __restrict__ R,
    float* __restrict__ mbuf, float* __restrict__ vbuf,
    float* __restrict__ out, int n, int first, float ib1, float ib2)
{
    int i = blockIdx.x * blockDim.x + threadIdx.x;
    if (i >= n) return;

    float xi0, xi1, xi2, pi0, pi1, pi2;
    load3(xyz, i, xi0, xi1, xi2);
    load3(recon, i, pi0, pi1, pi2);

    const float* Ri = R + (size_t)i * 9;
    float Ri0 = Ri[0], Ri1 = Ri[1], Ri2 = Ri[2];
    float Ri3 = Ri[3], Ri4 = Ri[4], Ri5 = Ri[5];
    float Ri6 = Ri[6], Ri7 = Ri[7], Ri8 = Ri[8];

    int e0 = acc[i];
    int cnt = num[i];

    float g0 = 0.f, g1 = 0.f, g2 = 0.f;
    for (int e = e0; e < e0 + cnt; ++e) {
        int j = nbr[e];
        float w = wm[e];
        float xj0, xj1, xj2, pj0, pj1, pj2;
        load3(xyz, j, xj0, xj1, xj2);
        load3(recon, j, pj0, pj1, pj2);
        const float* Rj = R + (size_t)j * 9;
        float r00 = Ri0 + Rj[0], r01 = Ri1 + Rj[1], r02 = Ri2 + Rj[2];
        float r10 = Ri3 + Rj[3], r11 = Ri4 + Rj[4], r12 = Ri5 + Rj[5];
        float r20 = Ri6 + Rj[6], r21 = Ri7 + Rj[7], r22 = Ri8 + Rj[8];
        float ei0 = xi0 - xj0, ei1 = xi1 - xj1, ei2 = xi2 - xj2;
        float ed0 = pi0 - pj0, ed1 = pi1 - pj1, ed2 = pi2 - pj2;
        float t0 = 2.f * ed0 - (r00 * ei0 + r01 * ei1 + r02 * ei2);
        float t1 = 2.f * ed1 - (r10 * ei0 + r11 * ei1 + r12 * ei2);
        float t2 = 2.f * ed2 - (r20 * ei0 + r21 * ei1 + r22 * ei2);
        g0 += w * t0; g1 += w * t1; g2 += w * t2;
    }

    float aw = arapW[0];
    g0 *= aw; g1 *= aw; g2 *= aw;

    const float B1 = 0.9f, B2 = 0.999f;
    float m0, m1, m2, v0, v1, v2;
    if (first) {
        m0 = (1.f - B1) * g0; m1 = (1.f - B1) * g1; m2 = (1.f - B1) * g2;
        v0 = (1.f - B2) * g0 * g0; v1 = (1.f - B2) * g1 * g1; v2 = (1.f - B2) * g2 * g2;
    } else {
        m0 = B1 * mbuf[3*i+0] + (1.f - B1) * g0;
        m1 = B1 * mbuf[3*i+1] + (1.f - B1) * g1;
        m2 = B1 * mbuf[3*i+2] + (1.f - B1) * g2;
        v0 = B2 * vbuf[3*i+0] + (1.f - B2) * g0 * g0;
        v1 = B2 * vbuf[3*i+1] + (1.f - B2) * g1 * g1;
        v2 = B2 * vbuf[3*i+2] + (1.f - B2) * g2 * g2;
    }
    mbuf[3*i+0] = m0; mbuf[3*i+1] = m1; mbuf[3*i+2] = m2;
    vbuf[3*i+0] = v0; vbuf[3*i+1] = v1; vbuf[3*i+2] = v2;

    float mh0 = m0 * ib1, mh1 = m1 * ib1, mh2 = m2 * ib1;
    float vh0 = v0 * ib2, vh1 = v1 * ib2, vh2 = v2 * ib2;

    const float RATE = 0.01f, EPS = 1e-9f;
    out[3*i+0] = pi0 - RATE * (mh0 / (sqrtf(vh0) + EPS));
    out[3*i+1] = pi1 - RATE * (mh1 / (sqrtf(vh1) + EPS));
    out[3*i+2] = pi2 - RATE * (mh2 / (sqrtf(vh2) + EPS));
}

extern "C" void kernel_launch(void* const* d_in, const int* in_sizes, int n_in,
                              void* d_out, int out_size, void* d_ws, size_t ws_size,
                              hipStream_t stream) {
    const float* xyz    = (const float*)d_in[0];
    const float* recon0 = (const float*)d_in[1];
    const int*   nbr    = (const int*)d_in[2];
    const int*   num    = (const int*)d_in[3];
    const int*   acc    = (const int*)d_in[4];
    const float* wm     = (const float*)d_in[5];
    const float* aw     = (const float*)d_in[6];

    int n = in_sizes[0] / 3;
    float* out = (float*)d_out;

    float* R    = (float*)d_ws;            // n*9
    float* mbuf = R    + (size_t)n * 9;    // n*3
    float* vbuf = mbuf + (size_t)n * 3;    // n*3
    float* bufA = vbuf + (size_t)n * 3;    // n*3
    float* bufB = bufA + (size_t)n * 3;    // n*3

    int grid = (n + BLK - 1) / BLK;

    const float* cur = recon0;
    for (int step = 1; step <= 8; ++step) {
        rot_kernel<<<grid, BLK, 0, stream>>>(xyz, cur, nbr, num, acc, wm, R, n);
        float* next = (step == 8) ? out : ((step & 1) ? bufA : bufB);
        float ib1 = 1.0f / (1.0f - powf(0.9f,   (float)step));
        float ib2 = 1.0f / (1.0f - powf(0.999f, (float)step));
        grad_adam_kernel<<<grid, BLK, 0, stream>>>(xyz, cur, nbr, num, acc, wm,
                                                   aw, R, mbuf, vbuf, next, n,
                                                   step == 1 ? 1 : 0, ib1, ib2);
        cur = next;
    }
}